// Round 2
// baseline (1332.115 us; speedup 1.0000x reference)
//
#include <hip/hip_runtime.h>
#include <hip/hip_bf16.h>
#include <cstdint>

#define B_   2
#define S_   2048
#define HID_ 3072
#define H_   16
#define KV_  8
#define D_   256
#define HD_  4096   // H_*D_
#define KVD_ 2048   // KV_*D_

constexpr float EPS_   = 1e-6f;
constexpr float SCALE_ = 0.0625f;   // 256^-0.5

typedef unsigned short u16;
typedef __attribute__((ext_vector_type(8))) short bf16x8;
typedef __attribute__((ext_vector_type(4))) float f32x4;

__device__ inline float bf2f(u16 u) { return __uint_as_float(((unsigned int)u) << 16); }
__device__ inline u16 f2bf(float f) {
  unsigned int x = __float_as_uint(f);
  x += 0x7fffu + ((x >> 16) & 1u);   // RNE
  return (u16)(x >> 16);
}

// async global->LDS, 16B per lane; lds base must be wave-uniform, data lands at base + lane*16
__device__ inline void gll16(const u16* g, u16* l) {
  __builtin_amdgcn_global_load_lds((const __attribute__((address_space(1))) unsigned int*)g,
                                   (__attribute__((address_space(3))) unsigned int*)l,
                                   16, 0, 0);
}

// ---------------- elementwise cast f32 -> bf16 (n4 = n/4) ----------------
__global__ void cast_f32_bf16(const float* __restrict__ in, u16* __restrict__ out, int n4) {
  int i = blockIdx.x * blockDim.x + threadIdx.x;
  if (i < n4) {
    float4 v = ((const float4*)in)[i];
    ushort4 o;
    o.x = f2bf(v.x); o.y = f2bf(v.y); o.z = f2bf(v.z); o.w = f2bf(v.w);
    ((ushort4*)out)[i] = o;
  }
}

// ------------- transpose+cast: in[K][N] f32 -> out[N][K] bf16 -------------
__global__ void transpose_cast(const float* __restrict__ in, u16* __restrict__ out, int K, int N) {
  __shared__ __align__(16) float tile[64][65];
  int n0 = blockIdx.x * 64, k0 = blockIdx.y * 64;
  int t = threadIdx.x;
  int rr = t >> 4, cc = (t & 15) * 4;
  for (int i = 0; i < 4; i++) {
    float4 v = *(const float4*)(&in[(size_t)(k0 + rr + 16 * i) * N + n0 + cc]);
    tile[rr + 16 * i][cc + 0] = v.x; tile[rr + 16 * i][cc + 1] = v.y;
    tile[rr + 16 * i][cc + 2] = v.z; tile[rr + 16 * i][cc + 3] = v.w;
  }
  __syncthreads();
  for (int i = 0; i < 4; i++) {
    int orow = rr + 16 * i;  // n index
    ushort4 o;
    o.x = f2bf(tile[cc + 0][orow]); o.y = f2bf(tile[cc + 1][orow]);
    o.z = f2bf(tile[cc + 2][orow]); o.w = f2bf(tile[cc + 3][orow]);
    *(ushort4*)(&out[(size_t)(n0 + orow) * K + k0 + cc]) = o;
  }
}

// --------- GEMM: C[M][N] = A[M][K] * Bt[N][K]^T, bf16 in, f32 acc ---------
// m97 structure: 128x128 tile, BK=32, global_load_lds width-16, unpadded stride-32 LDS
template <bool OUTF32>
__global__ __launch_bounds__(256) void gemm_bf16(const u16* __restrict__ A,
                                                 const u16* __restrict__ Bt,
                                                 void* __restrict__ Cv, int M, int N, int K) {
  __shared__ __align__(16) u16 As[128 * 32];
  __shared__ __align__(16) u16 Bs[128 * 32];
  int t = threadIdx.x, lane = t & 63, wave = t >> 6;
  int wm = wave >> 1, wn = wave & 1, quad = lane >> 4, l16 = lane & 15;
  int bm = blockIdx.y * 128, bn = blockIdx.x * 128;
  f32x4 acc[4][4] = {};
  // staging: lane l of wave w owns row w*16 + l/4 (plus +64 for second half), 16B chunk l&3
  int srow = wave * 16 + (lane >> 2);
  int scol = (lane & 3) * 8;
  const u16* ap0 = A  + (size_t)(bm + srow) * K + scol;
  const u16* ap1 = A  + (size_t)(bm + 64 + srow) * K + scol;
  const u16* bp0 = Bt + (size_t)(bn + srow) * K + scol;
  const u16* bp1 = Bt + (size_t)(bn + 64 + srow) * K + scol;
  u16* asb0 = &As[wave * 512];
  u16* asb1 = &As[wave * 512 + 2048];
  u16* bsb0 = &Bs[wave * 512];
  u16* bsb1 = &Bs[wave * 512 + 2048];
  for (int k0 = 0; k0 < K; k0 += 32) {
    __syncthreads();
    gll16(ap0 + k0, asb0);
    gll16(ap1 + k0, asb1);
    gll16(bp0 + k0, bsb0);
    gll16(bp1 + k0, bsb1);
    __syncthreads();
    bf16x8 af[4], bfr[4];
    for (int i = 0; i < 4; i++)
      af[i] = *(const bf16x8*)(&As[(wm * 64 + i * 16 + l16) * 32 + quad * 8]);
    for (int j = 0; j < 4; j++)
      bfr[j] = *(const bf16x8*)(&Bs[(wn * 64 + j * 16 + l16) * 32 + quad * 8]);
    for (int i = 0; i < 4; i++)
      for (int j = 0; j < 4; j++)
        acc[i][j] = __builtin_amdgcn_mfma_f32_16x16x32_bf16(af[i], bfr[j], acc[i][j], 0, 0, 0);
  }
  for (int i = 0; i < 4; i++)
    for (int j = 0; j < 4; j++)
      for (int r = 0; r < 4; r++) {
        int row = bm + wm * 64 + i * 16 + quad * 4 + r;
        int col = bn + wn * 64 + j * 16 + l16;
        float v = acc[i][j][r];
        if (OUTF32) ((float*)Cv)[(size_t)row * N + col] = v;
        else ((u16*)Cv)[(size_t)row * N + col] = f2bf(v);
      }
}

// ----- fused RMSNorm + RoPE, in place on bf16 [B*S][nh][256]; 1 wave/head -----
__global__ void rmsnorm_rope(u16* __restrict__ x, const float* __restrict__ w,
                             const float* __restrict__ fc, const float* __restrict__ fsn,
                             int nh, float outscale) {
  int token = blockIdx.x;
  int head = blockIdx.y * 4 + (threadIdx.x >> 6);
  if (head >= nh) return;
  int lane = threadIdx.x & 63;
  int s = token & (S_ - 1);
  u16* p = x + (size_t)(token * nh + head) * D_;
  float v0 = bf2f(p[lane]);
  float v1 = bf2f(p[lane + 64]);
  float v2 = bf2f(p[lane + 128]);
  float v3 = bf2f(p[lane + 192]);
  float ss = v0 * v0 + v1 * v1 + v2 * v2 + v3 * v3;
  for (int off = 32; off; off >>= 1) ss += __shfl_xor(ss, off, 64);
  float rs = rsqrtf(ss * (1.0f / D_) + EPS_);
  float n0 = v0 * rs * (1.0f + w[lane]);
  float n1 = v1 * rs * (1.0f + w[lane + 64]);
  float n2 = v2 * rs * (1.0f + w[lane + 128]);
  float n3 = v3 * rs * (1.0f + w[lane + 192]);
  float c0 = fc[s * 128 + lane], s0 = fsn[s * 128 + lane];
  float c1 = fc[s * 128 + lane + 64], s1 = fsn[s * 128 + lane + 64];
  p[lane]       = f2bf((n0 * c0 - n2 * s0) * outscale);
  p[lane + 128] = f2bf((n0 * s0 + n2 * c0) * outscale);
  p[lane + 64]  = f2bf((n1 * c1 - n3 * s1) * outscale);
  p[lane + 192] = f2bf((n1 * s1 + n3 * c1) * outscale);
}

// ---------------- flash attention, causal, GQA rep=2, D=256 ----------------
// grid (S/64, H, B) longest-first; 256 threads; wave = 16 q rows; 32-key tiles
// K fragments read DIRECTLY from global (L1-shared across waves); only V staged in LDS
__global__ __launch_bounds__(256) void flash_attn(const u16* __restrict__ Q,
                                                  const u16* __restrict__ Kb,
                                                  const u16* __restrict__ Vb,
                                                  u16* __restrict__ O) {
  __shared__ __align__(16) u16 Vs[256 * 40];     // V transposed: Vt[d][key], padded
  __shared__ __align__(16) u16 Ps[4][16 * 32];   // per-wave P round-trip
  int t = threadIdx.x, lane = t & 63, wave = t >> 6;
  int quad = lane >> 4, l16 = lane & 15;
  int qb = ((int)gridDim.x - 1 - (int)blockIdx.x) * 64;  // longest blocks first
  int h = blockIdx.y, b = blockIdx.z;
  int kvh = h >> 1;
  int qw = qb + wave * 16;

  // Q fragments (A-layout) straight from global
  bf16x8 qf[8];
  const u16* qp = Q + ((size_t)(b * S_) + qw + l16) * HD_ + h * D_;
  for (int c = 0; c < 8; c++) qf[c] = *(const bf16x8*)(qp + c * 32 + quad * 8);

  f32x4 o_acc[16] = {};
  float m_r[4], l_r[4];
  for (int r = 0; r < 4; r++) { m_r[r] = -3e38f; l_r[r] = 0.f; }

  int nkt = (qb + 64) >> 5;
  const u16* kbase = Kb + (size_t)b * S_ * KVD_ + kvh * D_;
  const u16* vbase = Vb + (size_t)b * S_ * KVD_ + kvh * D_;

  for (int kt = 0; kt < nkt; kt++) {
    // ---- V staging: lane owns d=t, gathers 32 keys, packs, writes transposed ----
    u16 hold[32];
    const u16* vp = vbase + (size_t)(kt * 32) * KVD_ + t;
#pragma unroll
    for (int kk = 0; kk < 32; kk++) hold[kk] = vp[(size_t)kk * KVD_];
    __syncthreads();   // previous tile's PV reads done
#pragma unroll
    for (int g = 0; g < 4; g++) {
      uint4 wv;
      wv.x = (unsigned)hold[g * 8 + 0] | ((unsigned)hold[g * 8 + 1] << 16);
      wv.y = (unsigned)hold[g * 8 + 2] | ((unsigned)hold[g * 8 + 3] << 16);
      wv.z = (unsigned)hold[g * 8 + 4] | ((unsigned)hold[g * 8 + 5] << 16);
      wv.w = (unsigned)hold[g * 8 + 6] | ((unsigned)hold[g * 8 + 7] << 16);
      *(uint4*)(&Vs[t * 40 + g * 8]) = wv;
    }
    __syncthreads();

    // ---- QK: K fragments direct from global, two batches of 8 ----
    f32x4 sc0 = {}, sc1 = {};
    const u16* kp = kbase + (size_t)(kt * 32 + l16) * KVD_ + quad * 8;
#pragma unroll
    for (int cb = 0; cb < 2; cb++) {
      bf16x8 k0[4], k1[4];
#pragma unroll
      for (int cc = 0; cc < 4; cc++) {
        int c = cb * 4 + cc;
        k0[cc] = *(const bf16x8*)(kp + c * 32);
        k1[cc] = *(const bf16x8*)(kp + (size_t)16 * KVD_ + c * 32);
      }
#pragma unroll
      for (int cc = 0; cc < 4; cc++) {
        sc0 = __builtin_amdgcn_mfma_f32_16x16x32_bf16(qf[cb * 4 + cc], k0[cc], sc0, 0, 0, 0);
        sc1 = __builtin_amdgcn_mfma_f32_16x16x32_bf16(qf[cb * 4 + cc], k1[cc], sc1, 0, 0, 0);
      }
    }

    // ---- online softmax with wave-uniform alpha-skip ----
    int kg0 = kt * 32 + l16, kg1 = kg0 + 16;
    float p0[4], p1[4], mnew[4];
    bool chg = false;
#pragma unroll
    for (int r = 0; r < 4; r++) {
      int qg = qw + quad * 4 + r;
      float a  = (kg0 <= qg) ? sc0[r] : -1e30f;
      float bb = (kg1 <= qg) ? sc1[r] : -1e30f;
      float mx = fmaxf(a, bb);
      for (int off = 1; off < 16; off <<= 1) mx = fmaxf(mx, __shfl_xor(mx, off, 16));
      float mn = fmaxf(m_r[r], mx);
      mnew[r] = mn;
      chg = chg || (mn > m_r[r]);
      p0[r] = __expf(a - mn);
      p1[r] = __expf(bb - mn);
    }
    if (__any((int)chg)) {   // wave-uniform: skip rescale when no row max moved (alpha==1 exactly)
      float alpha[4];
#pragma unroll
      for (int r = 0; r < 4; r++) alpha[r] = __expf(m_r[r] - mnew[r]);
#pragma unroll
      for (int nt = 0; nt < 16; nt++)
        for (int r = 0; r < 4; r++) o_acc[nt][r] *= alpha[r];
#pragma unroll
      for (int r = 0; r < 4; r++) l_r[r] *= alpha[r];
    }
#pragma unroll
    for (int r = 0; r < 4; r++) {
      m_r[r] = mnew[r];
      float rsum = p0[r] + p1[r];
      for (int off = 1; off < 16; off <<= 1) rsum += __shfl_xor(rsum, off, 16);
      l_r[r] += rsum;
    }

    // ---- P: C-layout -> LDS -> A-layout ----
    u16* pw = &Ps[wave][0];
#pragma unroll
    for (int r = 0; r < 4; r++) {
      pw[(quad * 4 + r) * 32 + l16] = f2bf(p0[r]);
      pw[(quad * 4 + r) * 32 + l16 + 16] = f2bf(p1[r]);
    }
    asm volatile("s_waitcnt lgkmcnt(0)" ::: "memory");
    bf16x8 pf = *(const bf16x8*)(&pw[l16 * 32 + quad * 8]);
#pragma unroll
    for (int nt = 0; nt < 16; nt++) {
      bf16x8 vf = *(const bf16x8*)(&Vs[(nt * 16 + l16) * 40 + quad * 8]);
      o_acc[nt] = __builtin_amdgcn_mfma_f32_16x16x32_bf16(pf, vf, o_acc[nt], 0, 0, 0);
    }
  }
  // epilogue: O / l
  for (int r = 0; r < 4; r++) {
    int qg = qw + quad * 4 + r;
    float inv = 1.0f / l_r[r];
    u16* op = O + ((size_t)(b * S_) + qg) * HD_ + h * D_;
    for (int nt = 0; nt < 16; nt++) op[nt * 16 + l16] = f2bf(o_acc[nt][r] * inv);
  }
}

extern "C" void kernel_launch(void* const* d_in, const int* in_sizes, int n_in,
                              void* d_out, int out_size, void* d_ws, size_t ws_size,
                              hipStream_t stream) {
  const float* hs  = (const float*)d_in[0];
  const float* fc  = (const float*)d_in[1];
  const float* fsn = (const float*)d_in[2];
  // d_in[3] = mask: causal, replicated analytically
  const float* qw  = (const float*)d_in[4];
  const float* kw  = (const float*)d_in[5];
  const float* vw  = (const float*)d_in[6];
  const float* ow  = (const float*)d_in[7];
  const float* qnw = (const float*)d_in[8];
  const float* knw = (const float*)d_in[9];

  char* ws = (char*)d_ws;
  // layout (bytes):
  u16* x_bf = (u16*)(ws + 0);           // 4096*3072*2  = 25165824
  u16* qw_t = (u16*)(ws + 25165824);    // 4096*3072*2  = 25165824
  u16* kw_t = (u16*)(ws + 50331648);    // 2048*3072*2  = 12582912
  u16* vw_t = (u16*)(ws + 62914560);    // 2048*3072*2  = 12582912
  u16* ow_t = (u16*)(ws + 75497472);    // 3072*4096*2  = 25165824
  u16* xq   = (u16*)(ws + 100663296);   // 4096*4096*2  = 33554432
  u16* xk   = (u16*)(ws + 134217728);   // 4096*2048*2  = 16777216
  u16* xv   = (u16*)(ws + 150994944);   // 4096*2048*2  = 16777216  -> end 167772160
  u16* attn = (u16*)(ws + 25165824);    // overlays dead qw_t/kw_t region (33.5MB <= 37.7MB)

  cast_f32_bf16<<<12288, 256, 0, stream>>>(hs, x_bf, 4096 * 3072 / 4);
  transpose_cast<<<dim3(64, 48), 256, 0, stream>>>(qw, qw_t, 3072, 4096);
  transpose_cast<<<dim3(32, 48), 256, 0, stream>>>(kw, kw_t, 3072, 2048);
  transpose_cast<<<dim3(32, 48), 256, 0, stream>>>(vw, vw_t, 3072, 2048);
  transpose_cast<<<dim3(48, 64), 256, 0, stream>>>(ow, ow_t, 4096, 3072);

  gemm_bf16<false><<<dim3(32, 32), 256, 0, stream>>>(x_bf, qw_t, xq, 4096, 4096, 3072);
  gemm_bf16<false><<<dim3(16, 32), 256, 0, stream>>>(x_bf, kw_t, xk, 4096, 2048, 3072);
  gemm_bf16<false><<<dim3(16, 32), 256, 0, stream>>>(x_bf, vw_t, xv, 4096, 2048, 3072);

  rmsnorm_rope<<<dim3(4096, 4), 256, 0, stream>>>(xq, qnw, fc, fsn, 16, SCALE_);
  rmsnorm_rope<<<dim3(4096, 2), 256, 0, stream>>>(xk, knw, fc, fsn, 8, 1.0f);

  flash_attn<<<dim3(32, 16, 2), 256, 0, stream>>>(xq, xk, xv, attn);

  gemm_bf16<true><<<dim3(24, 32), 256, 0, stream>>>(attn, ow_t, (float*)d_out, 4096, 3072, 4096);
}

// Round 3
// 1038.133 us; speedup vs baseline: 1.2832x; 1.2832x over previous
//
#include <hip/hip_runtime.h>
#include <hip/hip_bf16.h>
#include <cstdint>

#define B_   2
#define S_   2048
#define HID_ 3072
#define H_   16
#define KV_  8
#define D_   256
#define HD_  4096   // H_*D_
#define KVD_ 2048   // KV_*D_

constexpr float EPS_   = 1e-6f;
constexpr float SCALE_ = 0.0625f;   // 256^-0.5

typedef unsigned short u16;
typedef __attribute__((ext_vector_type(8))) short bf16x8;
typedef __attribute__((ext_vector_type(4))) float f32x4;

__device__ inline float bf2f(u16 u) { return __uint_as_float(((unsigned int)u) << 16); }
__device__ inline u16 f2bf(float f) {
  unsigned int x = __float_as_uint(f);
  x += 0x7fffu + ((x >> 16) & 1u);   // RNE
  return (u16)(x >> 16);
}

// async global->LDS, 16B per lane; lds base must be wave-uniform, data lands at base + lane*16
__device__ inline void gll16(const u16* g, u16* l) {
  __builtin_amdgcn_global_load_lds((const __attribute__((address_space(1))) unsigned int*)g,
                                   (__attribute__((address_space(3))) unsigned int*)l,
                                   16, 0, 0);
}

// ---------------- elementwise cast f32 -> bf16 (n4 = n/4) ----------------
__global__ void cast_f32_bf16(const float* __restrict__ in, u16* __restrict__ out, int n4) {
  int i = blockIdx.x * blockDim.x + threadIdx.x;
  if (i < n4) {
    float4 v = ((const float4*)in)[i];
    ushort4 o;
    o.x = f2bf(v.x); o.y = f2bf(v.y); o.z = f2bf(v.z); o.w = f2bf(v.w);
    ((ushort4*)out)[i] = o;
  }
}

// ------------- transpose+cast: in[K][N] f32 -> out[N][K] bf16 -------------
__global__ void transpose_cast(const float* __restrict__ in, u16* __restrict__ out, int K, int N) {
  __shared__ __align__(16) float tile[64][65];
  int n0 = blockIdx.x * 64, k0 = blockIdx.y * 64;
  int t = threadIdx.x;
  int rr = t >> 4, cc = (t & 15) * 4;
  for (int i = 0; i < 4; i++) {
    float4 v = *(const float4*)(&in[(size_t)(k0 + rr + 16 * i) * N + n0 + cc]);
    tile[rr + 16 * i][cc + 0] = v.x; tile[rr + 16 * i][cc + 1] = v.y;
    tile[rr + 16 * i][cc + 2] = v.z; tile[rr + 16 * i][cc + 3] = v.w;
  }
  __syncthreads();
  for (int i = 0; i < 4; i++) {
    int orow = rr + 16 * i;  // n index
    ushort4 o;
    o.x = f2bf(tile[cc + 0][orow]); o.y = f2bf(tile[cc + 1][orow]);
    o.z = f2bf(tile[cc + 2][orow]); o.w = f2bf(tile[cc + 3][orow]);
    *(ushort4*)(&out[(size_t)(n0 + orow) * K + k0 + cc]) = o;
  }
}

// ------- bf16 transpose: in[4096 tok][2048 n] -> out[b][2048 n][2048 s] -------
__global__ void transpose_v(const u16* __restrict__ in, u16* __restrict__ out) {
  __shared__ __align__(16) u16 tile[64][68];
  int n0 = blockIdx.x * 64, tk0 = blockIdx.y * 64;
  int b = tk0 >> 11, s0 = tk0 & (S_ - 1);
  int t = threadIdx.x;
  int rr = t >> 4, cc = (t & 15) * 4;
  for (int i = 0; i < 4; i++) {
    ushort4 v = *(const ushort4*)(&in[(size_t)(tk0 + rr + 16 * i) * KVD_ + n0 + cc]);
    tile[rr + 16 * i][cc + 0] = v.x; tile[rr + 16 * i][cc + 1] = v.y;
    tile[rr + 16 * i][cc + 2] = v.z; tile[rr + 16 * i][cc + 3] = v.w;
  }
  __syncthreads();
  for (int i = 0; i < 4; i++) {
    int orow = rr + 16 * i;  // n index
    ushort4 o;
    o.x = tile[cc + 0][orow]; o.y = tile[cc + 1][orow];
    o.z = tile[cc + 2][orow]; o.w = tile[cc + 3][orow];
    *(ushort4*)(&out[((size_t)b << 22) + (size_t)(n0 + orow) * S_ + s0 + cc]) = o;
  }
}

// --------- GEMM: C[M][N] = A[M][K] * Bt[N][K]^T, bf16 in, f32 acc ---------
// m97 structure: 128x128 tile, BK=32, global_load_lds width-16, unpadded stride-32 LDS
template <bool OUTF32>
__global__ __launch_bounds__(256) void gemm_bf16(const u16* __restrict__ A,
                                                 const u16* __restrict__ Bt,
                                                 void* __restrict__ Cv, int M, int N, int K) {
  __shared__ __align__(16) u16 As[128 * 32];
  __shared__ __align__(16) u16 Bs[128 * 32];
  int t = threadIdx.x, lane = t & 63, wave = t >> 6;
  int wm = wave >> 1, wn = wave & 1, quad = lane >> 4, l16 = lane & 15;
  int bm = blockIdx.y * 128, bn = blockIdx.x * 128;
  f32x4 acc[4][4] = {};
  int srow = wave * 16 + (lane >> 2);
  int scol = (lane & 3) * 8;
  const u16* ap0 = A  + (size_t)(bm + srow) * K + scol;
  const u16* ap1 = A  + (size_t)(bm + 64 + srow) * K + scol;
  const u16* bp0 = Bt + (size_t)(bn + srow) * K + scol;
  const u16* bp1 = Bt + (size_t)(bn + 64 + srow) * K + scol;
  u16* asb0 = &As[wave * 512];
  u16* asb1 = &As[wave * 512 + 2048];
  u16* bsb0 = &Bs[wave * 512];
  u16* bsb1 = &Bs[wave * 512 + 2048];
  for (int k0 = 0; k0 < K; k0 += 32) {
    __syncthreads();
    gll16(ap0 + k0, asb0);
    gll16(ap1 + k0, asb1);
    gll16(bp0 + k0, bsb0);
    gll16(bp1 + k0, bsb1);
    __syncthreads();
    bf16x8 af[4], bfr[4];
    for (int i = 0; i < 4; i++)
      af[i] = *(const bf16x8*)(&As[(wm * 64 + i * 16 + l16) * 32 + quad * 8]);
    for (int j = 0; j < 4; j++)
      bfr[j] = *(const bf16x8*)(&Bs[(wn * 64 + j * 16 + l16) * 32 + quad * 8]);
    for (int i = 0; i < 4; i++)
      for (int j = 0; j < 4; j++)
        acc[i][j] = __builtin_amdgcn_mfma_f32_16x16x32_bf16(af[i], bfr[j], acc[i][j], 0, 0, 0);
  }
  for (int i = 0; i < 4; i++)
    for (int j = 0; j < 4; j++)
      for (int r = 0; r < 4; r++) {
        int row = bm + wm * 64 + i * 16 + quad * 4 + r;
        int col = bn + wn * 64 + j * 16 + l16;
        float v = acc[i][j][r];
        if (OUTF32) ((float*)Cv)[(size_t)row * N + col] = v;
        else ((u16*)Cv)[(size_t)row * N + col] = f2bf(v);
      }
}

// ----- fused RMSNorm + RoPE, in place on bf16 [B*S][nh][256]; 1 wave/head -----
__global__ void rmsnorm_rope(u16* __restrict__ x, const float* __restrict__ w,
                             const float* __restrict__ fc, const float* __restrict__ fsn,
                             int nh, float outscale) {
  int token = blockIdx.x;
  int head = blockIdx.y * 4 + (threadIdx.x >> 6);
  if (head >= nh) return;
  int lane = threadIdx.x & 63;
  int s = token & (S_ - 1);
  u16* p = x + (size_t)(token * nh + head) * D_;
  float v0 = bf2f(p[lane]);
  float v1 = bf2f(p[lane + 64]);
  float v2 = bf2f(p[lane + 128]);
  float v3 = bf2f(p[lane + 192]);
  float ss = v0 * v0 + v1 * v1 + v2 * v2 + v3 * v3;
  for (int off = 32; off; off >>= 1) ss += __shfl_xor(ss, off, 64);
  float rs = rsqrtf(ss * (1.0f / D_) + EPS_);
  float n0 = v0 * rs * (1.0f + w[lane]);
  float n1 = v1 * rs * (1.0f + w[lane + 64]);
  float n2 = v2 * rs * (1.0f + w[lane + 128]);
  float n3 = v3 * rs * (1.0f + w[lane + 192]);
  float c0 = fc[s * 128 + lane], s0 = fsn[s * 128 + lane];
  float c1 = fc[s * 128 + lane + 64], s1 = fsn[s * 128 + lane + 64];
  p[lane]       = f2bf((n0 * c0 - n2 * s0) * outscale);
  p[lane + 128] = f2bf((n0 * s0 + n2 * c0) * outscale);
  p[lane + 64]  = f2bf((n1 * c1 - n3 * s1) * outscale);
  p[lane + 192] = f2bf((n1 * s1 + n3 * c1) * outscale);
}

// ---------------- flash attention, causal, GQA rep=2, D=256 ----------------
// grid (S/64, H, B) longest-first; 256 threads; wave = 16 q rows; 32-key tiles.
// K and V^T staged via global_load_lds into conflict-free chunked LDS layouts.
__global__ __launch_bounds__(256, 4) void flash_attn(const u16* __restrict__ Q,
                                                     const u16* __restrict__ Kb,
                                                     const u16* __restrict__ Vt,
                                                     u16* __restrict__ O) {
  __shared__ __align__(16) u16 Ks[8 * 1024];     // [chunk c][key 0..31][d-sub 0..31]
  __shared__ __align__(16) u16 Vs[256 * 32];     // [d 0..255][key 0..31]
  __shared__ __align__(16) u16 Ps[4][16 * 32];   // per-wave P round-trip
  int t = threadIdx.x, lane = t & 63, wave = t >> 6;
  int quad = lane >> 4, l16 = lane & 15;
  int qb = ((int)gridDim.x - 1 - (int)blockIdx.x) * 64;  // longest blocks first
  int h = blockIdx.y, b = blockIdx.z;
  int kvh = h >> 1;
  int qw = qb + wave * 16;

  // Q fragments (A-layout) straight from global
  bf16x8 qf[8];
  const u16* qp = Q + ((size_t)(b * S_) + qw + l16) * HD_ + h * D_;
  for (int c = 0; c < 8; c++) qf[c] = *(const bf16x8*)(qp + c * 32 + quad * 8);

  f32x4 o_acc[16] = {};
  float m_r[4], l_r[4];
  for (int r = 0; r < 4; r++) { m_r[r] = -3e38f; l_r[r] = 0.f; }

  int nkt = (qb + 64) >> 5;
  // K staging: wave w stages d-chunks 2w,2w+1 for all 32 keys (2 rounds each)
  const u16* kst = Kb + (size_t)(b * S_ + (lane >> 2)) * KVD_ + kvh * D_ + wave * 64 + (lane & 3) * 8;
  u16* kdst = &Ks[wave * 2048];
  // V staging: wave w stages d rows w*64..w*64+63 (4 rounds of 16 rows)
  const u16* vst = Vt + ((size_t)b << 22) + (size_t)(kvh * D_ + wave * 64 + (lane >> 2)) * S_ + (lane & 3) * 8;
  u16* vdst = &Vs[wave * 64 * 32];

  for (int kt = 0; kt < nkt; kt++) {
    __syncthreads();   // prior tile's LDS reads complete
    // K: chunk c2 in {0,1} (d-sub = wave*64 + c2*32), rounds r in {0,1} (keys r*16..)
#pragma unroll
    for (int c2 = 0; c2 < 2; c2++)
#pragma unroll
      for (int r = 0; r < 2; r++)
        gll16(kst + (size_t)(kt * 32 + r * 16) * KVD_ + c2 * 32, kdst + c2 * 1024 + r * 512);
    // V: 4 rounds of 16 d-rows
#pragma unroll
    for (int c = 0; c < 4; c++)
      gll16(vst + (size_t)(c * 16) * S_ + kt * 32, vdst + c * 512);
    __syncthreads();   // drains vmcnt, all staged

    // ---- QK: two 16x16 C-tiles over 8 d-chunks ----
    f32x4 sc0 = {}, sc1 = {};
#pragma unroll
    for (int c = 0; c < 8; c++) {
      bf16x8 k0 = *(const bf16x8*)(&Ks[c * 1024 + l16 * 32 + quad * 8]);
      bf16x8 k1 = *(const bf16x8*)(&Ks[c * 1024 + (l16 + 16) * 32 + quad * 8]);
      sc0 = __builtin_amdgcn_mfma_f32_16x16x32_bf16(qf[c], k0, sc0, 0, 0, 0);
      sc1 = __builtin_amdgcn_mfma_f32_16x16x32_bf16(qf[c], k1, sc1, 0, 0, 0);
    }

    // ---- online softmax with wave-uniform alpha-skip ----
    int kg0 = kt * 32 + l16, kg1 = kg0 + 16;
    float p0[4], p1[4], mnew[4];
    bool chg = false;
#pragma unroll
    for (int r = 0; r < 4; r++) {
      int qg = qw + quad * 4 + r;
      float a  = (kg0 <= qg) ? sc0[r] : -1e30f;
      float bb = (kg1 <= qg) ? sc1[r] : -1e30f;
      float mx = fmaxf(a, bb);
      for (int off = 1; off < 16; off <<= 1) mx = fmaxf(mx, __shfl_xor(mx, off, 16));
      float mn = fmaxf(m_r[r], mx);
      mnew[r] = mn;
      chg = chg || (mn > m_r[r]);
      p0[r] = __expf(a - mn);
      p1[r] = __expf(bb - mn);
    }
    if (__any((int)chg)) {   // alpha==1 exactly when no row max moved
      float alpha[4];
#pragma unroll
      for (int r = 0; r < 4; r++) alpha[r] = __expf(m_r[r] - mnew[r]);
#pragma unroll
      for (int nt = 0; nt < 16; nt++)
        for (int r = 0; r < 4; r++) o_acc[nt][r] *= alpha[r];
#pragma unroll
      for (int r = 0; r < 4; r++) l_r[r] *= alpha[r];
    }
#pragma unroll
    for (int r = 0; r < 4; r++) {
      m_r[r] = mnew[r];
      float rsum = p0[r] + p1[r];
      for (int off = 1; off < 16; off <<= 1) rsum += __shfl_xor(rsum, off, 16);
      l_r[r] += rsum;
    }

    // ---- P: C-layout -> LDS -> A-layout ----
    u16* pw = &Ps[wave][0];
#pragma unroll
    for (int r = 0; r < 4; r++) {
      pw[(quad * 4 + r) * 32 + l16] = f2bf(p0[r]);
      pw[(quad * 4 + r) * 32 + l16 + 16] = f2bf(p1[r]);
    }
    asm volatile("s_waitcnt lgkmcnt(0)" ::: "memory");
    bf16x8 pf = *(const bf16x8*)(&pw[l16 * 32 + quad * 8]);
#pragma unroll
    for (int nt = 0; nt < 16; nt++) {
      bf16x8 vf = *(const bf16x8*)(&Vs[(nt * 16 + l16) * 32 + quad * 8]);
      o_acc[nt] = __builtin_amdgcn_mfma_f32_16x16x32_bf16(pf, vf, o_acc[nt], 0, 0, 0);
    }
  }
  // epilogue: O / l
  for (int r = 0; r < 4; r++) {
    int qg = qw + quad * 4 + r;
    float inv = 1.0f / l_r[r];
    u16* op = O + ((size_t)(b * S_) + qg) * HD_ + h * D_;
    for (int nt = 0; nt < 16; nt++) op[nt * 16 + l16] = f2bf(o_acc[nt][r] * inv);
  }
}

extern "C" void kernel_launch(void* const* d_in, const int* in_sizes, int n_in,
                              void* d_out, int out_size, void* d_ws, size_t ws_size,
                              hipStream_t stream) {
  const float* hs  = (const float*)d_in[0];
  const float* fc  = (const float*)d_in[1];
  const float* fsn = (const float*)d_in[2];
  // d_in[3] = mask: causal, replicated analytically
  const float* qw  = (const float*)d_in[4];
  const float* kw  = (const float*)d_in[5];
  const float* vw  = (const float*)d_in[6];
  const float* ow  = (const float*)d_in[7];
  const float* qnw = (const float*)d_in[8];
  const float* knw = (const float*)d_in[9];

  char* ws = (char*)d_ws;
  // layout (bytes):
  u16* x_bf = (u16*)(ws + 0);           // 4096*3072*2  = 25165824 (dead after GEMMs)
  u16* vt   = (u16*)(ws + 0);           // 2*2048*2048*2 = 16777216 (overlays dead x_bf)
  u16* qw_t = (u16*)(ws + 25165824);    // 4096*3072*2  = 25165824
  u16* kw_t = (u16*)(ws + 50331648);    // 2048*3072*2  = 12582912
  u16* vw_t = (u16*)(ws + 62914560);    // 2048*3072*2  = 12582912
  u16* ow_t = (u16*)(ws + 75497472);    // 3072*4096*2  = 25165824
  u16* xq   = (u16*)(ws + 100663296);   // 4096*4096*2  = 33554432
  u16* xk   = (u16*)(ws + 134217728);   // 4096*2048*2  = 16777216
  u16* xv   = (u16*)(ws + 150994944);   // 4096*2048*2  = 16777216  -> end 167772160
  u16* attn = (u16*)(ws + 25165824);    // overlays dead qw_t/kw_t region (33.5MB <= 37.7MB)

  cast_f32_bf16<<<12288, 256, 0, stream>>>(hs, x_bf, 4096 * 3072 / 4);
  transpose_cast<<<dim3(64, 48), 256, 0, stream>>>(qw, qw_t, 3072, 4096);
  transpose_cast<<<dim3(32, 48), 256, 0, stream>>>(kw, kw_t, 3072, 2048);
  transpose_cast<<<dim3(32, 48), 256, 0, stream>>>(vw, vw_t, 3072, 2048);
  transpose_cast<<<dim3(48, 64), 256, 0, stream>>>(ow, ow_t, 4096, 3072);

  gemm_bf16<false><<<dim3(32, 32), 256, 0, stream>>>(x_bf, qw_t, xq, 4096, 4096, 3072);
  gemm_bf16<false><<<dim3(16, 32), 256, 0, stream>>>(x_bf, kw_t, xk, 4096, 2048, 3072);
  gemm_bf16<false><<<dim3(16, 32), 256, 0, stream>>>(x_bf, vw_t, xv, 4096, 2048, 3072);

  rmsnorm_rope<<<dim3(4096, 4), 256, 0, stream>>>(xq, qnw, fc, fsn, 16, SCALE_);
  rmsnorm_rope<<<dim3(4096, 2), 256, 0, stream>>>(xk, knw, fc, fsn, 8, 1.0f);

  transpose_v<<<dim3(32, 64), 256, 0, stream>>>(xv, vt);

  flash_attn<<<dim3(32, 16, 2), 256, 0, stream>>>(xq, xk, vt, attn);

  gemm_bf16<true><<<dim3(24, 32), 256, 0, stream>>>(attn, ow_t, (float*)d_out, 4096, 3072, 4096);
}